// Round 7
// baseline (327.101 us; speedup 1.0000x reference)
//
#include <hip/hip_runtime.h>
#include <hip/hip_bf16.h>
#include <math.h>

// Problem constants (fixed by the reference setup)
constexpr int B = 8;
constexpr int V = 262144;
constexpr int J = 64;
constexpr int K = 4;
constexpr int G = 2048;
constexpr int L = 8;
constexpr int E = 1835008;
constexpr float EPS = 1e-8f;
constexpr int NBLK = V / 256;   // 1024 scan blocks
constexpr int NBKT = 8;         // XCD buckets
constexpr int VPB = V / NBKT;   // 32768 keys per bucket
constexpr int BKT_GRID = 8192;  // blocks for bucketed kernels
constexpr int NMW = 16;         // padded node stride: 16 floats = 64 B (1 line)

__device__ inline unsigned bf16bits(float x) {
  unsigned u = __float_as_uint(x);
  return (u + 0x7fffu + ((u >> 16) & 1u)) >> 16;  // round-to-nearest-even
}

// ---------------------------------------------------------------------------
// Kernel 0: per (b,j) normalized joint quat + dual part jd = 0.5*qmul((0,t),q)
// ---------------------------------------------------------------------------
__global__ __launch_bounds__(256) void jqd_kernel(
    const float* __restrict__ jquat, const float* __restrict__ jtrans,
    float* __restrict__ ws) {
  int i = blockIdx.x * blockDim.x + threadIdx.x;
  if (i >= B * J) return;
  float qw = jquat[i * 4 + 0];
  float qx = jquat[i * 4 + 1];
  float qy = jquat[i * 4 + 2];
  float qz = jquat[i * 4 + 3];
  float inv = 1.0f / (sqrtf(qw * qw + qx * qx + qy * qy + qz * qz) + EPS);
  qw *= inv; qx *= inv; qy *= inv; qz *= inv;
  float tx = jtrans[i * 3 + 0];
  float ty = jtrans[i * 3 + 1];
  float tz = jtrans[i * 3 + 2];
  float dw = -0.5f * (tx * qx + ty * qy + tz * qz);
  float dx = 0.5f * (qw * tx + (ty * qz - tz * qy));
  float dy = 0.5f * (qw * ty + (tz * qx - tx * qz));
  float dz = 0.5f * (qw * tz + (tx * qy - ty * qx));
  float* o = ws + (size_t)i * 8;
  o[0] = qw; o[1] = qx; o[2] = qy; o[3] = qz;
  o[4] = dw; o[5] = dx; o[6] = dy; o[7] = dz;
}

// ---------------------------------------------------------------------------
// Kernel 0b: per (b,g) affine transform, PADDED to one 64 B line per node.
// warped = M*p + T, T = gp + nt - M*gp. Words 0..11 = {row0,row1,row2} as
// float4 {m,m,m,t}; words 12..15 unused pad (never read).
// ---------------------------------------------------------------------------
__global__ __launch_bounds__(256) void nmat_kernel(
    const float* __restrict__ npos, const float* __restrict__ nquat,
    const float* __restrict__ ntrans, float* __restrict__ nmt) {
  int i = blockIdx.x * blockDim.x + threadIdx.x;
  if (i >= B * G) return;
  int g = i & (G - 1);
  float4 q = *reinterpret_cast<const float4*>(nquat + (size_t)i * 4);
  float qw = q.x, qx = q.y, qy = q.z, qz = q.w;
  float inv = 1.0f / (sqrtf(qw * qw + qx * qx + qy * qy + qz * qz) + EPS);
  qw *= inv; qx *= inv; qy *= inv; qz *= inv;
  float xx = qx * qx, yy = qy * qy, zz = qz * qz;
  float xy = qx * qy, xz = qx * qz, yz = qy * qz;
  float wx = qw * qx, wy = qw * qy, wz = qw * qz;
  float m00 = 1.f - 2.f * (yy + zz), m01 = 2.f * (xy - wz), m02 = 2.f * (xz + wy);
  float m10 = 2.f * (xy + wz), m11 = 1.f - 2.f * (xx + zz), m12 = 2.f * (yz - wx);
  float m20 = 2.f * (xz - wy), m21 = 2.f * (yz + wx), m22 = 1.f - 2.f * (xx + yy);
  float gx = npos[g * 3 + 0], gy = npos[g * 3 + 1], gz = npos[g * 3 + 2];
  float tx = ntrans[(size_t)i * 3 + 0] + gx - (m00 * gx + m01 * gy + m02 * gz);
  float ty = ntrans[(size_t)i * 3 + 1] + gy - (m10 * gx + m11 * gy + m12 * gz);
  float tz = ntrans[(size_t)i * 3 + 2] + gz - (m20 * gx + m21 * gy + m22 * gz);
  float4* o = reinterpret_cast<float4*>(nmt + (size_t)i * NMW);
  o[0] = make_float4(m00, m01, m02, tx);
  o[1] = make_float4(m10, m11, m12, ty);
  o[2] = make_float4(m20, m21, m22, tz);
}

// ---------------------------------------------------------------------------
// Kernel 1: posed4 — direct global gather from line-padded nmt.
// One thread per vertex, all B batches. Each link = exactly one 64 B L2 line.
// mode: 0 = write pvm16, 1 = no pvm16, 2 = no pvm16 + zero lap
// ---------------------------------------------------------------------------
__global__ __launch_bounds__(256) void posed4_kernel(
    const float* __restrict__ tv, const float* __restrict__ sw_in,
    const float* __restrict__ lw_in, const int* __restrict__ sidx,
    const int* __restrict__ lidx, const float* __restrict__ nmt,
    const float* __restrict__ jqd, float* __restrict__ out,
    unsigned* __restrict__ pvm16, int mode) {
  int v = blockIdx.x * blockDim.x + threadIdx.x;
  if (v >= V) return;

  float px = tv[(size_t)v * 3 + 0];
  float py = tv[(size_t)v * 3 + 1];
  float pz = tv[(size_t)v * 3 + 2];

  int4 si = *reinterpret_cast<const int4*>(sidx + (size_t)v * 4);
  float4 swv = *reinterpret_cast<const float4*>(sw_in + (size_t)v * 4);
  int4 li0 = *reinterpret_cast<const int4*>(lidx + (size_t)v * 8);
  int4 li1 = *reinterpret_cast<const int4*>(lidx + (size_t)v * 8 + 4);
  float4 lw0 = *reinterpret_cast<const float4*>(lw_in + (size_t)v * 8);
  float4 lw1 = *reinterpret_cast<const float4*>(lw_in + (size_t)v * 8 + 4);

  float sinv = 1.0f / (swv.x + swv.y + swv.z + swv.w + EPS);
  float swn[K] = {swv.x * sinv, swv.y * sinv, swv.z * sinv, swv.w * sinv};
  int sj[K] = {si.x, si.y, si.z, si.w};

  float linv =
      1.0f / (lw0.x + lw0.y + lw0.z + lw0.w + lw1.x + lw1.y + lw1.z + lw1.w + EPS);
  float lwn[L] = {lw0.x * linv, lw0.y * linv, lw0.z * linv, lw0.w * linv,
                  lw1.x * linv, lw1.y * linv, lw1.z * linv, lw1.w * linv};
  int gi[L] = {li0.x * NMW, li0.y * NMW, li0.z * NMW, li0.w * NMW,
               li1.x * NMW, li1.y * NMW, li1.z * NMW, li1.w * NMW};

  constexpr size_t LAPOFF = (size_t)B * V * 3;
  unsigned pk[2 * B];

  for (int b = 0; b < B; ++b) {
    const float* mt_b = nmt + (size_t)b * G * NMW;

    // ---- v_eg = sum_l lw * (M p + T); each link reads one 64 B line ----
    float ex = 0.f, ey = 0.f, ez = 0.f;
#pragma unroll
    for (int l = 0; l < L; ++l) {
      const float4* m = reinterpret_cast<const float4*>(mt_b + gi[l]);
      float4 r0 = m[0], r1 = m[1], r2 = m[2];
      float w = lwn[l];
      ex += w * (r0.x * px + r0.y * py + r0.z * pz + r0.w);
      ey += w * (r1.x * px + r1.y * py + r1.z * pz + r1.w);
      ez += w * (r2.x * px + r2.y * py + r2.z * pz + r2.w);
    }

    // ---- joint dual-quat blend (jqd slice is 2 KB/batch, L1-hot) ----
    float rbw = 0.f, rbx = 0.f, rby = 0.f, rbz = 0.f;
    float dbw = 0.f, dbx = 0.f, dby = 0.f, dbz = 0.f;
    float r0w = 0.f, r0x = 0.f, r0y = 0.f, r0z = 0.f;
#pragma unroll
    for (int k = 0; k < K; ++k) {
      const float* eptr = jqd + ((size_t)b * J + sj[k]) * 8;
      float4 qf = *reinterpret_cast<const float4*>(eptr);
      float4 df = *reinterpret_cast<const float4*>(eptr + 4);
      float qw = qf.x, qx = qf.y, qy = qf.z, qz = qf.w;
      if (k == 0) { r0w = qw; r0x = qx; r0y = qy; r0z = qz; }
      float dotr = qw * r0w + qx * r0x + qy * r0y + qz * r0z;
      float s = (dotr >= 0.0f) ? swn[k] : -swn[k];
      rbw += s * qw; rbx += s * qx; rby += s * qy; rbz += s * qz;
      dbw += s * df.x; dbx += s * df.y; dby += s * df.z; dbz += s * df.w;
    }
    float ninv = 1.0f / (sqrtf(rbw * rbw + rbx * rbx + rby * rby + rbz * rbz) + EPS);
    rbw *= ninv; rbx *= ninv; rby *= ninv; rbz *= ninv;
    dbw *= ninv; dbx *= ninv; dby *= ninv; dbz *= ninv;

    float txx = 2.0f * (rbw * dbx - dbw * rbx + (rby * dbz - rbz * dby));
    float tyy = 2.0f * (rbw * dby - dbw * rby + (rbz * dbx - rbx * dbz));
    float tzz = 2.0f * (rbw * dbz - dbw * rbz + (rbx * dby - rby * dbx));

    float cx = rby * ez - rbz * ey + rbw * ex;
    float cy = rbz * ex - rbx * ez + rbw * ey;
    float cz = rbx * ey - rby * ex + rbw * ez;
    float ox = ex + 2.0f * (rby * cz - rbz * cy) + txx;
    float oy = ey + 2.0f * (rbz * cx - rbx * cz) + tyy;
    float oz = ez + 2.0f * (rbx * cy - rby * cx) + tzz;

    size_t o = ((size_t)b * V + v) * 3;
    out[o + 0] = ox; out[o + 1] = oy; out[o + 2] = oz;
    pk[b * 2 + 0] = bf16bits(ox) | (bf16bits(oy) << 16);
    pk[b * 2 + 1] = bf16bits(oz);
    if (mode == 2) {
      out[LAPOFF + o + 0] = 0.f;
      out[LAPOFF + o + 1] = 0.f;
      out[LAPOFF + o + 2] = 0.f;
    }
  }

  if (mode == 0) {
    uint4* dst = reinterpret_cast<uint4*>(pvm16 + (size_t)v * 16);
    dst[0] = make_uint4(pk[0], pk[1], pk[2], pk[3]);
    dst[1] = make_uint4(pk[4], pk[5], pk[6], pk[7]);
    dst[2] = make_uint4(pk[8], pk[9], pk[10], pk[11]);
    dst[3] = make_uint4(pk[12], pk[13], pk[14], pk[15]);
  }
}

// ---------------------------------------------------------------------------
// CSR build: XCD-bucketed histogram -> scan -> XCD-bucketed scatter.
// ---------------------------------------------------------------------------
__global__ __launch_bounds__(256) void hist_bucketed_kernel(
    const int* __restrict__ st, int* __restrict__ cnt) {
  int p = blockIdx.x & (NBKT - 1);
  int lo = p * VPB, hi = lo + VPB;
  int stride = (gridDim.x / NBKT) * 256;
  for (int e = (blockIdx.x / NBKT) * 256 + (int)threadIdx.x; e < E; e += stride) {
    int s = st[e];
    if (s >= lo && s < hi) atomicAdd(&cnt[s], 1);
  }
}

__global__ __launch_bounds__(256) void scan1_kernel(const int* __restrict__ cnt,
                                                    int* __restrict__ excl,
                                                    int* __restrict__ bsum) {
  __shared__ int s[256];
  int t = threadIdx.x;
  int i = blockIdx.x * 256 + t;
  int x = cnt[i];
  s[t] = x;
  __syncthreads();
  for (int off = 1; off < 256; off <<= 1) {
    int val = (t >= off) ? s[t - off] : 0;
    __syncthreads();
    s[t] += val;
    __syncthreads();
  }
  excl[i] = s[t] - x;
  if (t == 255) bsum[blockIdx.x] = s[t];
}

__global__ __launch_bounds__(1024) void scan2_kernel(const int* __restrict__ bsum,
                                                     int* __restrict__ boff) {
  __shared__ int s[NBLK];
  int t = threadIdx.x;
  int x = bsum[t];
  s[t] = x;
  __syncthreads();
  for (int off = 1; off < NBLK; off <<= 1) {
    int val = (t >= off) ? s[t - off] : 0;
    __syncthreads();
    s[t] += val;
    __syncthreads();
  }
  boff[t] = s[t] - x;
}

__global__ __launch_bounds__(256) void scan3_kernel(int* __restrict__ excl,
                                                    const int* __restrict__ boff,
                                                    int* __restrict__ cursor) {
  int i = blockIdx.x * 256 + threadIdx.x;
  int r = excl[i] + boff[blockIdx.x];
  excl[i] = r;
  cursor[i] = r;
  if (i == 0) excl[V] = E;
}

__global__ __launch_bounds__(256) void scatter_bucketed_kernel(
    const int* __restrict__ st, const int* __restrict__ ed,
    const float* __restrict__ w, int* __restrict__ cursor,
    int2* __restrict__ e2) {
  int p = blockIdx.x & (NBKT - 1);
  int lo = p * VPB, hi = lo + VPB;
  int stride = (gridDim.x / NBKT) * 256;
  for (int e = (blockIdx.x / NBKT) * 256 + (int)threadIdx.x; e < E; e += stride) {
    int s = st[e];
    if (s >= lo && s < hi) {
      int pos = atomicAdd(&cursor[s], 1);
      e2[pos] = make_int2(ed[e], __float_as_int(w[e]));
    }
  }
}

// ---------------------------------------------------------------------------
// Gather from bf16 vertex-major pvm16 ([v][b][2]u32): one 64 B line per edge.
// ---------------------------------------------------------------------------
__global__ __launch_bounds__(256) void lap_gather_pvm16_kernel(
    const int* __restrict__ rowstart, const int2* __restrict__ e2,
    const unsigned* __restrict__ pvm16, float* __restrict__ lap) {
  int v = blockIdx.x * blockDim.x + threadIdx.x;
  if (v >= V) return;
  int beg = rowstart[v];
  int end = rowstart[v + 1];
  float acc[B][3];
#pragma unroll
  for (int b = 0; b < B; ++b) { acc[b][0] = 0.f; acc[b][1] = 0.f; acc[b][2] = 0.f; }
  for (int j = beg; j < end; ++j) {
    int2 ew = e2[j];
    float w = __int_as_float(ew.y);
    const uint4* p = reinterpret_cast<const uint4*>(pvm16 + (size_t)ew.x * 16);
    uint4 q0 = p[0], q1 = p[1], q2 = p[2], q3 = p[3];
    unsigned u[16] = {q0.x, q0.y, q0.z, q0.w, q1.x, q1.y, q1.z, q1.w,
                      q2.x, q2.y, q2.z, q2.w, q3.x, q3.y, q3.z, q3.w};
#pragma unroll
    for (int b = 0; b < B; ++b) {
      acc[b][0] += w * __uint_as_float(u[2 * b] << 16);
      acc[b][1] += w * __uint_as_float(u[2 * b] & 0xffff0000u);
      acc[b][2] += w * __uint_as_float(u[2 * b + 1] << 16);
    }
  }
#pragma unroll
  for (int b = 0; b < B; ++b) {
    size_t o = ((size_t)b * V + v) * 3;
    lap[o + 0] = acc[b][0];
    lap[o + 1] = acc[b][1];
    lap[o + 2] = acc[b][2];
  }
}

// Tier-B gather: from batch-major posed (= out) if ws can't hold pvm16.
__global__ __launch_bounds__(256) void lap_gather_bm_kernel(
    const int* __restrict__ rowstart, const int2* __restrict__ e2,
    const float* __restrict__ posed, float* __restrict__ lap) {
  int v = blockIdx.x * blockDim.x + threadIdx.x;
  if (v >= V) return;
  int beg = rowstart[v];
  int end = rowstart[v + 1];
  float acc[B][3];
#pragma unroll
  for (int b = 0; b < B; ++b) { acc[b][0] = 0.f; acc[b][1] = 0.f; acc[b][2] = 0.f; }
  for (int j = beg; j < end; ++j) {
    int2 ew = e2[j];
    float w = __int_as_float(ew.y);
    const float* p = posed + (size_t)ew.x * 3;
#pragma unroll
    for (int b = 0; b < B; ++b) {
      const float* pb = p + (size_t)b * V * 3;
      acc[b][0] += w * pb[0];
      acc[b][1] += w * pb[1];
      acc[b][2] += w * pb[2];
    }
  }
#pragma unroll
  for (int b = 0; b < B; ++b) {
    size_t o = ((size_t)b * V + v) * 3;
    lap[o + 0] = acc[b][0];
    lap[o + 1] = acc[b][1];
    lap[o + 2] = acc[b][2];
  }
}

// Tier-C fallback: per-edge atomic scatter.
__global__ __launch_bounds__(256) void lap_atomic_kernel(
    const float* __restrict__ lapw, const int* __restrict__ st,
    const int* __restrict__ ed, const float* __restrict__ posed,
    float* __restrict__ lap) {
  int e = blockIdx.x * blockDim.x + threadIdx.x;
  if (e >= E) return;
  float w = lapw[e];
  int s = st[e];
  int d = ed[e];
#pragma unroll
  for (int b = 0; b < B; ++b) {
    size_t pb = ((size_t)b * V + d) * 3;
    size_t ob = ((size_t)b * V + s) * 3;
    atomicAdd(&lap[ob + 0], w * posed[pb + 0]);
    atomicAdd(&lap[ob + 1], w * posed[pb + 1]);
    atomicAdd(&lap[ob + 2], w * posed[pb + 2]);
  }
}

extern "C" void kernel_launch(void* const* d_in, const int* in_sizes, int n_in,
                              void* d_out, int out_size, void* d_ws, size_t ws_size,
                              hipStream_t stream) {
  const float* tv    = (const float*)d_in[0];
  const float* jquat = (const float*)d_in[1];
  const float* jtran = (const float*)d_in[2];
  const float* sw    = (const float*)d_in[3];
  const float* npos  = (const float*)d_in[4];
  const float* nquat = (const float*)d_in[5];
  const float* ntran = (const float*)d_in[6];
  const float* lw    = (const float*)d_in[7];
  const float* lapw  = (const float*)d_in[8];
  const int*   sidx  = (const int*)d_in[9];
  const int*   lidx  = (const int*)d_in[10];
  const int*   lst   = (const int*)d_in[11];
  const int*   led   = (const int*)d_in[12];
  float* out = (float*)d_out;
  float* lap = out + (size_t)B * V * 3;

  // workspace layout (jqd at 0 is 64B-aligned; nmt at 16 KB is 64B-aligned)
  float*    jqd      = (float*)d_ws;                    // 4096 f (16 KB)
  float*    nmt      = jqd + 4096;                      // B*G*16 f (1 MB)
  int2*     e2       = (int2*)(nmt + (size_t)B * G * NMW);  // E int2 (14.68 MB)
  unsigned* pvm16    = (unsigned*)(e2 + E);             // V*16 u32 (16.78 MB)
  int*      cnt      = (int*)(pvm16 + (size_t)V * 16);  // V
  int*      rowstart = cnt + V;                         // V+1
  int*      cursor   = rowstart + V + 1;                // V
  int*      bsum     = cursor + V;                      // NBLK
  int*      boff     = bsum + NBLK;                     // NBLK
  size_t needA = (size_t)((char*)(boff + NBLK) - (char*)d_ws);
  size_t needB = needA - (size_t)V * 16 * sizeof(unsigned);
  int tier = (ws_size >= needA) ? 0 : (ws_size >= needB) ? 1 : 2;

  if (tier == 1) {
    // shift CSR arrays down over the pvm16 hole
    cnt = (int*)(e2 + E);
    rowstart = cnt + V;
    cursor = rowstart + V + 1;
    bsum = cursor + V;
    boff = bsum + NBLK;
  }

  jqd_kernel<<<(B * J + 255) / 256, 256, 0, stream>>>(jquat, jtran, jqd);
  nmat_kernel<<<(B * G + 255) / 256, 256, 0, stream>>>(npos, nquat, ntran, nmt);
  posed4_kernel<<<V / 256, 256, 0, stream>>>(tv, sw, lw, sidx, lidx, nmt, jqd,
                                             out, pvm16, tier);
  if (tier <= 1) {
    hipMemsetAsync(cnt, 0, (size_t)V * sizeof(int), stream);
    hist_bucketed_kernel<<<BKT_GRID, 256, 0, stream>>>(lst, cnt);
    scan1_kernel<<<NBLK, 256, 0, stream>>>(cnt, rowstart, bsum);
    scan2_kernel<<<1, NBLK, 0, stream>>>(bsum, boff);
    scan3_kernel<<<NBLK, 256, 0, stream>>>(rowstart, boff, cursor);
    scatter_bucketed_kernel<<<BKT_GRID, 256, 0, stream>>>(lst, led, lapw,
                                                          cursor, e2);
    if (tier == 0) {
      lap_gather_pvm16_kernel<<<V / 256, 256, 0, stream>>>(rowstart, e2, pvm16,
                                                           lap);
    } else {
      lap_gather_bm_kernel<<<V / 256, 256, 0, stream>>>(rowstart, e2, out, lap);
    }
  } else {
    lap_atomic_kernel<<<E / 256, 256, 0, stream>>>(lapw, lst, led, out, lap);
  }
}

// Round 8
// 293.952 us; speedup vs baseline: 1.1128x; 1.1128x over previous
//
#include <hip/hip_runtime.h>
#include <hip/hip_bf16.h>
#include <math.h>

// Problem constants (fixed by the reference setup)
constexpr int B = 8;
constexpr int V = 262144;
constexpr int J = 64;
constexpr int K = 4;
constexpr int G = 2048;
constexpr int L = 8;
constexpr int E = 1835008;
constexpr float EPS = 1e-8f;
constexpr int NBLK = V / 256;   // 1024 scan blocks
constexpr int NBKT = 8;         // XCD buckets
constexpr int VPB = V / NBKT;   // 32768 keys per bucket
constexpr int BKT_GRID = 8192;  // blocks for bucketed kernels
constexpr int PT5 = 1024;       // posed5 block size (1 block/CU, 16 waves)

__device__ inline unsigned bf16bits(float x) {
  unsigned u = __float_as_uint(x);
  return (u + 0x7fffu + ((u >> 16) & 1u)) >> 16;  // round-to-nearest-even
}

// ---------------------------------------------------------------------------
// Kernel 0: per (b,j) normalized joint quat + dual part jd = 0.5*qmul((0,t),q)
// ---------------------------------------------------------------------------
__global__ __launch_bounds__(256) void jqd_kernel(
    const float* __restrict__ jquat, const float* __restrict__ jtrans,
    float* __restrict__ ws) {
  int i = blockIdx.x * blockDim.x + threadIdx.x;
  if (i >= B * J) return;
  float qw = jquat[i * 4 + 0];
  float qx = jquat[i * 4 + 1];
  float qy = jquat[i * 4 + 2];
  float qz = jquat[i * 4 + 3];
  float inv = 1.0f / (sqrtf(qw * qw + qx * qx + qy * qy + qz * qz) + EPS);
  qw *= inv; qx *= inv; qy *= inv; qz *= inv;
  float tx = jtrans[i * 3 + 0];
  float ty = jtrans[i * 3 + 1];
  float tz = jtrans[i * 3 + 2];
  float dw = -0.5f * (tx * qx + ty * qy + tz * qz);
  float dx = 0.5f * (qw * tx + (ty * qz - tz * qy));
  float dy = 0.5f * (qw * ty + (tz * qx - tx * qz));
  float dz = 0.5f * (qw * tz + (tx * qy - ty * qx));
  float* o = ws + (size_t)i * 8;
  o[0] = qw; o[1] = qx; o[2] = qy; o[3] = qz;
  o[4] = dw; o[5] = dx; o[6] = dy; o[7] = dz;
}

// ---------------------------------------------------------------------------
// Kernel 0b: per (b,g) affine transform, packed [G][3]float4 per batch.
// warped = M*p + T, T = gp + nt - M*gp. Row r = float4 {m_r0,m_r1,m_r2,t_r}.
// ---------------------------------------------------------------------------
__global__ __launch_bounds__(256) void nmat_kernel(
    const float* __restrict__ npos, const float* __restrict__ nquat,
    const float* __restrict__ ntrans, float* __restrict__ nmt) {
  int i = blockIdx.x * blockDim.x + threadIdx.x;
  if (i >= B * G) return;
  int g = i & (G - 1);
  float4 q = *reinterpret_cast<const float4*>(nquat + (size_t)i * 4);
  float qw = q.x, qx = q.y, qy = q.z, qz = q.w;
  float inv = 1.0f / (sqrtf(qw * qw + qx * qx + qy * qy + qz * qz) + EPS);
  qw *= inv; qx *= inv; qy *= inv; qz *= inv;
  float xx = qx * qx, yy = qy * qy, zz = qz * qz;
  float xy = qx * qy, xz = qx * qz, yz = qy * qz;
  float wx = qw * qx, wy = qw * qy, wz = qw * qz;
  float m00 = 1.f - 2.f * (yy + zz), m01 = 2.f * (xy - wz), m02 = 2.f * (xz + wy);
  float m10 = 2.f * (xy + wz), m11 = 1.f - 2.f * (xx + zz), m12 = 2.f * (yz - wx);
  float m20 = 2.f * (xz - wy), m21 = 2.f * (yz + wx), m22 = 1.f - 2.f * (xx + yy);
  float gx = npos[g * 3 + 0], gy = npos[g * 3 + 1], gz = npos[g * 3 + 2];
  float tx = ntrans[(size_t)i * 3 + 0] + gx - (m00 * gx + m01 * gy + m02 * gz);
  float ty = ntrans[(size_t)i * 3 + 1] + gy - (m10 * gx + m11 * gy + m12 * gz);
  float tz = ntrans[(size_t)i * 3 + 2] + gz - (m20 * gx + m21 * gy + m22 * gz);
  float4* o = reinterpret_cast<float4*>(nmt + (size_t)i * 12);
  o[0] = make_float4(m00, m01, m02, tx);
  o[1] = make_float4(m10, m11, m12, ty);
  o[2] = make_float4(m20, m21, m22, tz);
}

// ---------------------------------------------------------------------------
// Kernel 1: posed5 — LDS-staged node table, ds_read_b128 gathers.
// 1024 threads/block, 256 blocks (1/CU). LDS = [G][3]float4 = 96 KB packed;
// staging is a straight contiguous float4 copy. Per link: 3 b128 LDS reads.
// mode: 0 = write pvm16, 1 = no pvm16, 2 = no pvm16 + zero lap
// ---------------------------------------------------------------------------
__global__ __launch_bounds__(PT5) void posed5_kernel(
    const float* __restrict__ tv, const float* __restrict__ sw_in,
    const float* __restrict__ lw_in, const int* __restrict__ sidx,
    const int* __restrict__ lidx, const float* __restrict__ nmt,
    const float* __restrict__ jqd, float* __restrict__ out,
    unsigned* __restrict__ pvm16, int mode) {
  extern __shared__ float4 sm4[];  // G*3 float4 = 98304 B
  int v = blockIdx.x * PT5 + threadIdx.x;

  float px = tv[(size_t)v * 3 + 0];
  float py = tv[(size_t)v * 3 + 1];
  float pz = tv[(size_t)v * 3 + 2];

  int4 si = *reinterpret_cast<const int4*>(sidx + (size_t)v * 4);
  float4 swv = *reinterpret_cast<const float4*>(sw_in + (size_t)v * 4);
  int4 li0 = *reinterpret_cast<const int4*>(lidx + (size_t)v * 8);
  int4 li1 = *reinterpret_cast<const int4*>(lidx + (size_t)v * 8 + 4);
  float4 lw0 = *reinterpret_cast<const float4*>(lw_in + (size_t)v * 8);
  float4 lw1 = *reinterpret_cast<const float4*>(lw_in + (size_t)v * 8 + 4);

  float sinv = 1.0f / (swv.x + swv.y + swv.z + swv.w + EPS);
  float swn[K] = {swv.x * sinv, swv.y * sinv, swv.z * sinv, swv.w * sinv};
  int sj[K] = {si.x, si.y, si.z, si.w};

  float linv =
      1.0f / (lw0.x + lw0.y + lw0.z + lw0.w + lw1.x + lw1.y + lw1.z + lw1.w + EPS);
  float lwn[L] = {lw0.x * linv, lw0.y * linv, lw0.z * linv, lw0.w * linv,
                  lw1.x * linv, lw1.y * linv, lw1.z * linv, lw1.w * linv};
  // float4 index of node's row 0 in LDS
  int gi[L] = {li0.x * 3, li0.y * 3, li0.z * 3, li0.w * 3,
               li1.x * 3, li1.y * 3, li1.z * 3, li1.w * 3};

  constexpr size_t LAPOFF = (size_t)B * V * 3;
  unsigned pk[2 * B];

  for (int b = 0; b < B; ++b) {
    __syncthreads();  // previous batch's reads done before restage
    const float4* src = reinterpret_cast<const float4*>(nmt + (size_t)b * G * 12);
#pragma unroll
    for (int it = 0; it < (G * 3) / PT5; ++it) {
      int q = it * PT5 + threadIdx.x;
      sm4[q] = src[q];
    }
    __syncthreads();

    // ---- v_eg = sum_l lw * (M p + T); 3x ds_read_b128 per link ----
    float ex = 0.f, ey = 0.f, ez = 0.f;
#pragma unroll
    for (int l = 0; l < L; ++l) {
      float4 r0 = sm4[gi[l] + 0];
      float4 r1 = sm4[gi[l] + 1];
      float4 r2 = sm4[gi[l] + 2];
      float w = lwn[l];
      ex += w * (r0.x * px + r0.y * py + r0.z * pz + r0.w);
      ey += w * (r1.x * px + r1.y * py + r1.z * pz + r1.w);
      ez += w * (r2.x * px + r2.y * py + r2.z * pz + r2.w);
    }

    // ---- joint dual-quat blend (jqd slice is 2 KB/batch, L1-hot) ----
    float rbw = 0.f, rbx = 0.f, rby = 0.f, rbz = 0.f;
    float dbw = 0.f, dbx = 0.f, dby = 0.f, dbz = 0.f;
    float r0w = 0.f, r0x = 0.f, r0y = 0.f, r0z = 0.f;
#pragma unroll
    for (int k = 0; k < K; ++k) {
      const float* eptr = jqd + ((size_t)b * J + sj[k]) * 8;
      float4 qf = *reinterpret_cast<const float4*>(eptr);
      float4 df = *reinterpret_cast<const float4*>(eptr + 4);
      float qw = qf.x, qx = qf.y, qy = qf.z, qz = qf.w;
      if (k == 0) { r0w = qw; r0x = qx; r0y = qy; r0z = qz; }
      float dotr = qw * r0w + qx * r0x + qy * r0y + qz * r0z;
      float s = (dotr >= 0.0f) ? swn[k] : -swn[k];
      rbw += s * qw; rbx += s * qx; rby += s * qy; rbz += s * qz;
      dbw += s * df.x; dbx += s * df.y; dby += s * df.z; dbz += s * df.w;
    }
    float ninv = 1.0f / (sqrtf(rbw * rbw + rbx * rbx + rby * rby + rbz * rbz) + EPS);
    rbw *= ninv; rbx *= ninv; rby *= ninv; rbz *= ninv;
    dbw *= ninv; dbx *= ninv; dby *= ninv; dbz *= ninv;

    float txx = 2.0f * (rbw * dbx - dbw * rbx + (rby * dbz - rbz * dby));
    float tyy = 2.0f * (rbw * dby - dbw * rby + (rbz * dbx - rbx * dbz));
    float tzz = 2.0f * (rbw * dbz - dbw * rbz + (rbx * dby - rby * dbx));

    float cx = rby * ez - rbz * ey + rbw * ex;
    float cy = rbz * ex - rbx * ez + rbw * ey;
    float cz = rbx * ey - rby * ex + rbw * ez;
    float ox = ex + 2.0f * (rby * cz - rbz * cy) + txx;
    float oy = ey + 2.0f * (rbz * cx - rbx * cz) + tyy;
    float oz = ez + 2.0f * (rbx * cy - rby * cx) + tzz;

    size_t o = ((size_t)b * V + v) * 3;
    out[o + 0] = ox; out[o + 1] = oy; out[o + 2] = oz;
    pk[b * 2 + 0] = bf16bits(ox) | (bf16bits(oy) << 16);
    pk[b * 2 + 1] = bf16bits(oz);
    if (mode == 2) {
      out[LAPOFF + o + 0] = 0.f;
      out[LAPOFF + o + 1] = 0.f;
      out[LAPOFF + o + 2] = 0.f;
    }
  }

  if (mode == 0) {
    uint4* dst = reinterpret_cast<uint4*>(pvm16 + (size_t)v * 16);
    dst[0] = make_uint4(pk[0], pk[1], pk[2], pk[3]);
    dst[1] = make_uint4(pk[4], pk[5], pk[6], pk[7]);
    dst[2] = make_uint4(pk[8], pk[9], pk[10], pk[11]);
    dst[3] = make_uint4(pk[12], pk[13], pk[14], pk[15]);
  }
}

// ---------------------------------------------------------------------------
// CSR build: XCD-bucketed histogram -> scan -> XCD-bucketed scatter.
// Keys vectorized as int4 (4x fewer load instructions).
// ---------------------------------------------------------------------------
__global__ __launch_bounds__(256) void hist_bucketed_kernel(
    const int* __restrict__ st, int* __restrict__ cnt) {
  int p = blockIdx.x & (NBKT - 1);
  int lo = p * VPB, hi = lo + VPB;
  const int4* st4 = reinterpret_cast<const int4*>(st);
  int n4 = E / 4;
  int stride = (gridDim.x / NBKT) * 256;
  for (int i = (blockIdx.x / NBKT) * 256 + (int)threadIdx.x; i < n4; i += stride) {
    int4 s = st4[i];
    if (s.x >= lo && s.x < hi) atomicAdd(&cnt[s.x], 1);
    if (s.y >= lo && s.y < hi) atomicAdd(&cnt[s.y], 1);
    if (s.z >= lo && s.z < hi) atomicAdd(&cnt[s.z], 1);
    if (s.w >= lo && s.w < hi) atomicAdd(&cnt[s.w], 1);
  }
}

__global__ __launch_bounds__(256) void scan1_kernel(const int* __restrict__ cnt,
                                                    int* __restrict__ excl,
                                                    int* __restrict__ bsum) {
  __shared__ int s[256];
  int t = threadIdx.x;
  int i = blockIdx.x * 256 + t;
  int x = cnt[i];
  s[t] = x;
  __syncthreads();
  for (int off = 1; off < 256; off <<= 1) {
    int val = (t >= off) ? s[t - off] : 0;
    __syncthreads();
    s[t] += val;
    __syncthreads();
  }
  excl[i] = s[t] - x;
  if (t == 255) bsum[blockIdx.x] = s[t];
}

__global__ __launch_bounds__(1024) void scan2_kernel(const int* __restrict__ bsum,
                                                     int* __restrict__ boff) {
  __shared__ int s[NBLK];
  int t = threadIdx.x;
  int x = bsum[t];
  s[t] = x;
  __syncthreads();
  for (int off = 1; off < NBLK; off <<= 1) {
    int val = (t >= off) ? s[t - off] : 0;
    __syncthreads();
    s[t] += val;
    __syncthreads();
  }
  boff[t] = s[t] - x;
}

__global__ __launch_bounds__(256) void scan3_kernel(int* __restrict__ excl,
                                                    const int* __restrict__ boff,
                                                    int* __restrict__ cursor) {
  int i = blockIdx.x * 256 + threadIdx.x;
  int r = excl[i] + boff[blockIdx.x];
  excl[i] = r;
  cursor[i] = r;
  if (i == 0) excl[V] = E;
}

__global__ __launch_bounds__(256) void scatter_bucketed_kernel(
    const int* __restrict__ st, const int* __restrict__ ed,
    const float* __restrict__ w, int* __restrict__ cursor,
    int2* __restrict__ e2) {
  int p = blockIdx.x & (NBKT - 1);
  int lo = p * VPB, hi = lo + VPB;
  const int4* st4 = reinterpret_cast<const int4*>(st);
  int n4 = E / 4;
  int stride = (gridDim.x / NBKT) * 256;
  for (int i = (blockIdx.x / NBKT) * 256 + (int)threadIdx.x; i < n4; i += stride) {
    int4 s = st4[i];
    int e = i * 4;
    if (s.x >= lo && s.x < hi) {
      int pos = atomicAdd(&cursor[s.x], 1);
      e2[pos] = make_int2(ed[e + 0], __float_as_int(w[e + 0]));
    }
    if (s.y >= lo && s.y < hi) {
      int pos = atomicAdd(&cursor[s.y], 1);
      e2[pos] = make_int2(ed[e + 1], __float_as_int(w[e + 1]));
    }
    if (s.z >= lo && s.z < hi) {
      int pos = atomicAdd(&cursor[s.z], 1);
      e2[pos] = make_int2(ed[e + 2], __float_as_int(w[e + 2]));
    }
    if (s.w >= lo && s.w < hi) {
      int pos = atomicAdd(&cursor[s.w], 1);
      e2[pos] = make_int2(ed[e + 3], __float_as_int(w[e + 3]));
    }
  }
}

// ---------------------------------------------------------------------------
// Gather from bf16 vertex-major pvm16 ([v][b][2]u32): one 64 B line per edge.
// ---------------------------------------------------------------------------
__global__ __launch_bounds__(256) void lap_gather_pvm16_kernel(
    const int* __restrict__ rowstart, const int2* __restrict__ e2,
    const unsigned* __restrict__ pvm16, float* __restrict__ lap) {
  int v = blockIdx.x * blockDim.x + threadIdx.x;
  if (v >= V) return;
  int beg = rowstart[v];
  int end = rowstart[v + 1];
  float acc[B][3];
#pragma unroll
  for (int b = 0; b < B; ++b) { acc[b][0] = 0.f; acc[b][1] = 0.f; acc[b][2] = 0.f; }
  for (int j = beg; j < end; ++j) {
    int2 ew = e2[j];
    float w = __int_as_float(ew.y);
    const uint4* p = reinterpret_cast<const uint4*>(pvm16 + (size_t)ew.x * 16);
    uint4 q0 = p[0], q1 = p[1], q2 = p[2], q3 = p[3];
    unsigned u[16] = {q0.x, q0.y, q0.z, q0.w, q1.x, q1.y, q1.z, q1.w,
                      q2.x, q2.y, q2.z, q2.w, q3.x, q3.y, q3.z, q3.w};
#pragma unroll
    for (int b = 0; b < B; ++b) {
      acc[b][0] += w * __uint_as_float(u[2 * b] << 16);
      acc[b][1] += w * __uint_as_float(u[2 * b] & 0xffff0000u);
      acc[b][2] += w * __uint_as_float(u[2 * b + 1] << 16);
    }
  }
#pragma unroll
  for (int b = 0; b < B; ++b) {
    size_t o = ((size_t)b * V + v) * 3;
    lap[o + 0] = acc[b][0];
    lap[o + 1] = acc[b][1];
    lap[o + 2] = acc[b][2];
  }
}

// Tier-B gather: from batch-major posed (= out) if ws can't hold pvm16.
__global__ __launch_bounds__(256) void lap_gather_bm_kernel(
    const int* __restrict__ rowstart, const int2* __restrict__ e2,
    const float* __restrict__ posed, float* __restrict__ lap) {
  int v = blockIdx.x * blockDim.x + threadIdx.x;
  if (v >= V) return;
  int beg = rowstart[v];
  int end = rowstart[v + 1];
  float acc[B][3];
#pragma unroll
  for (int b = 0; b < B; ++b) { acc[b][0] = 0.f; acc[b][1] = 0.f; acc[b][2] = 0.f; }
  for (int j = beg; j < end; ++j) {
    int2 ew = e2[j];
    float w = __int_as_float(ew.y);
    const float* p = posed + (size_t)ew.x * 3;
#pragma unroll
    for (int b = 0; b < B; ++b) {
      const float* pb = p + (size_t)b * V * 3;
      acc[b][0] += w * pb[0];
      acc[b][1] += w * pb[1];
      acc[b][2] += w * pb[2];
    }
  }
#pragma unroll
  for (int b = 0; b < B; ++b) {
    size_t o = ((size_t)b * V + v) * 3;
    lap[o + 0] = acc[b][0];
    lap[o + 1] = acc[b][1];
    lap[o + 2] = acc[b][2];
  }
}

// Tier-C fallback: per-edge atomic scatter.
__global__ __launch_bounds__(256) void lap_atomic_kernel(
    const float* __restrict__ lapw, const int* __restrict__ st,
    const int* __restrict__ ed, const float* __restrict__ posed,
    float* __restrict__ lap) {
  int e = blockIdx.x * blockDim.x + threadIdx.x;
  if (e >= E) return;
  float w = lapw[e];
  int s = st[e];
  int d = ed[e];
#pragma unroll
  for (int b = 0; b < B; ++b) {
    size_t pb = ((size_t)b * V + d) * 3;
    size_t ob = ((size_t)b * V + s) * 3;
    atomicAdd(&lap[ob + 0], w * posed[pb + 0]);
    atomicAdd(&lap[ob + 1], w * posed[pb + 1]);
    atomicAdd(&lap[ob + 2], w * posed[pb + 2]);
  }
}

extern "C" void kernel_launch(void* const* d_in, const int* in_sizes, int n_in,
                              void* d_out, int out_size, void* d_ws, size_t ws_size,
                              hipStream_t stream) {
  const float* tv    = (const float*)d_in[0];
  const float* jquat = (const float*)d_in[1];
  const float* jtran = (const float*)d_in[2];
  const float* sw    = (const float*)d_in[3];
  const float* npos  = (const float*)d_in[4];
  const float* nquat = (const float*)d_in[5];
  const float* ntran = (const float*)d_in[6];
  const float* lw    = (const float*)d_in[7];
  const float* lapw  = (const float*)d_in[8];
  const int*   sidx  = (const int*)d_in[9];
  const int*   lidx  = (const int*)d_in[10];
  const int*   lst   = (const int*)d_in[11];
  const int*   led   = (const int*)d_in[12];
  float* out = (float*)d_out;
  float* lap = out + (size_t)B * V * 3;

  // workspace layout (all segments 16B-aligned)
  float*    jqd      = (float*)d_ws;                    // 4096 f (16 KB)
  float*    nmt      = jqd + 4096;                      // B*G*12 f (786 KB)
  int2*     e2       = (int2*)(nmt + (size_t)B * G * 12);  // E int2 (14.68 MB)
  unsigned* pvm16    = (unsigned*)(e2 + E);             // V*16 u32 (16.78 MB)
  int*      cnt      = (int*)(pvm16 + (size_t)V * 16);  // V
  int*      rowstart = cnt + V;                         // V+1
  int*      cursor   = rowstart + V + 1;                // V
  int*      bsum     = cursor + V;                      // NBLK
  int*      boff     = bsum + NBLK;                     // NBLK
  size_t needA = (size_t)((char*)(boff + NBLK) - (char*)d_ws);
  size_t needB = needA - (size_t)V * 16 * sizeof(unsigned);
  int tier = (ws_size >= needA) ? 0 : (ws_size >= needB) ? 1 : 2;

  if (tier == 1) {
    // shift CSR arrays down over the pvm16 hole
    cnt = (int*)(e2 + E);
    rowstart = cnt + V;
    cursor = rowstart + V + 1;
    bsum = cursor + V;
    boff = bsum + NBLK;
  }

  jqd_kernel<<<(B * J + 255) / 256, 256, 0, stream>>>(jquat, jtran, jqd);
  nmat_kernel<<<(B * G + 255) / 256, 256, 0, stream>>>(npos, nquat, ntran, nmt);
  posed5_kernel<<<V / PT5, PT5, G * 3 * sizeof(float4), stream>>>(
      tv, sw, lw, sidx, lidx, nmt, jqd, out, pvm16, tier);
  if (tier <= 1) {
    hipMemsetAsync(cnt, 0, (size_t)V * sizeof(int), stream);
    hist_bucketed_kernel<<<BKT_GRID, 256, 0, stream>>>(lst, cnt);
    scan1_kernel<<<NBLK, 256, 0, stream>>>(cnt, rowstart, bsum);
    scan2_kernel<<<1, NBLK, 0, stream>>>(bsum, boff);
    scan3_kernel<<<NBLK, 256, 0, stream>>>(rowstart, boff, cursor);
    scatter_bucketed_kernel<<<BKT_GRID, 256, 0, stream>>>(lst, led, lapw,
                                                          cursor, e2);
    if (tier == 0) {
      lap_gather_pvm16_kernel<<<V / 256, 256, 0, stream>>>(rowstart, e2, pvm16,
                                                           lap);
    } else {
      lap_gather_bm_kernel<<<V / 256, 256, 0, stream>>>(rowstart, e2, out, lap);
    }
  } else {
    lap_atomic_kernel<<<E / 256, 256, 0, stream>>>(lapw, lst, led, out, lap);
  }
}